// Round 1
// baseline (1499.588 us; speedup 1.0000x reference)
//
#include <hip/hip_runtime.h>

// EmbeddingBag(mode='sum') over T tables.
//   weights: [T, V, D] fp32, lS_o: [T, B] int32 offsets, lS_i: [T, N] int32
//   out:     [T, B, D] fp32, out[t,b,:] = sum_{j in bag b} weights[t, lS_i[t,j], :]
//
// Memory-bound gather: 16 lanes per bag, float4 per lane -> one coalesced
// 256B row load per (bag, index). L=20 loop fully unrolled with indices
// pre-fetched to registers so all 20 gathers are independent (MLP latency
// hiding). Bags laid out t*B+b so same-table blocks run together (L3 reuse:
// each table = 51 MB < 256 MB Infinity Cache).

#define T_TABLES 26
#define V_VOCAB  200000
#define D_DIM    64
#define B_BATCH  4096
#define L_BAG    20
#define N_FLAT   (B_BATCH * L_BAG)

#define BAGS_PER_BLOCK 16  // 256 threads / 16 lanes-per-bag

__global__ __launch_bounds__(256) void embag_sum_kernel(
    const float* __restrict__ W,     // [T, V, D]
    const int*   __restrict__ offs,  // [T, B]
    const int*   __restrict__ idxs,  // [T, N]
    float*       __restrict__ out)   // [T, B, D]
{
    const int lane16 = threadIdx.x & 15;         // which float4 of the row
    const int group  = threadIdx.x >> 4;         // bag slot within block
    const long long bag = (long long)blockIdx.x * BAGS_PER_BLOCK + group; // t*B + b
    const int t = (int)(bag / B_BATCH);
    const int b = (int)(bag % B_BATCH);

    // Bag bounds from offsets (generic; reference guarantees fixed L=20).
    const int* offs_t = offs + (size_t)t * B_BATCH;
    const int start = offs_t[b];
    const int end   = (b + 1 < B_BATCH) ? offs_t[b + 1] : N_FLAT;
    const int len   = end - start;

    const int*   bag_idx = idxs + (size_t)t * N_FLAT + start;
    const float* Wt      = W + (size_t)t * ((size_t)V_VOCAB * D_DIM);

    float4 acc = make_float4(0.f, 0.f, 0.f, 0.f);

    if (len == L_BAG) {
        // Prefetch all 20 indices with two coalesced loads, broadcast via
        // shuffle so the 20 gathers below carry no load-load dependency.
        int ia = bag_idx[lane16];                                   // idx[0..15]
        int ib = (lane16 < (L_BAG - 16)) ? bag_idx[16 + lane16] : 0; // idx[16..19]
        #pragma unroll
        for (int j = 0; j < L_BAG; ++j) {
            int idx = (j < 16) ? __shfl(ia, j, 16) : __shfl(ib, j - 16, 16);
            const float4 v =
                *((const float4*)(Wt + (size_t)idx * D_DIM) + lane16);
            acc.x += v.x; acc.y += v.y; acc.z += v.z; acc.w += v.w;
        }
    } else {
        // Generic fallback (variable-length bags).
        for (int j = 0; j < len; ++j) {
            const int idx = bag_idx[j];
            const float4 v =
                *((const float4*)(Wt + (size_t)idx * D_DIM) + lane16);
            acc.x += v.x; acc.y += v.y; acc.z += v.z; acc.w += v.w;
        }
    }

    // Coalesced 256B store per bag; block writes 4 KB contiguous.
    ((float4*)out)[bag * (D_DIM / 4) + lane16] = acc;
}

extern "C" void kernel_launch(void* const* d_in, const int* in_sizes, int n_in,
                              void* d_out, int out_size, void* d_ws, size_t ws_size,
                              hipStream_t stream) {
    const float* W    = (const float*)d_in[0];
    const int*   lS_o = (const int*)d_in[1];
    const int*   lS_i = (const int*)d_in[2];
    float*       out  = (float*)d_out;

    const int total_bags = T_TABLES * B_BATCH;           // 106496
    const int grid       = total_bags / BAGS_PER_BLOCK;  // 6656

    embag_sum_kernel<<<grid, 256, 0, stream>>>(W, lS_o, lS_i, out);
}